// Round 10
// baseline (409.552 us; speedup 1.0000x reference)
//
#include <hip/hip_runtime.h>
#include <hip/hip_bf16.h>

typedef __attribute__((ext_vector_type(4))) float f32x4;
typedef __attribute__((ext_vector_type(8))) short short8;
typedef __attribute__((ext_vector_type(8))) __bf16 bf16x8;

#define NDIM 172
#define EDIM 172
#define TDIM 100
#define KCAT 444   // 172+172+100
#define KPAD 448
#define QDIM 272   // 172+100
#define ODIM 128
#define ZDIM 256
#define NNBR 32
#define KSTEP 64
#define NKS (KPAD / KSTEP)   // 7
#define LN_EPS 1e-5f

// ---- z_gemm LDS: A[0,32K) W0[32K,64K) W1[64K,96K); epilogue reuses [0,64K)
#define GW0 32768
#define GW1 65536
#define GEMM_LDS 98304

// ---- attn_tail LDS
#define AT_Q   65536
#define AT_P   67584
#define AT_O   68608
#define AT_R   70656
#define AT_LDS 70720

// Z/zsm byte offset with XOR bank-swizzle (row stride 512 B, 16B granular)
#define ZB(r,c) ((((r) * 512) + ((c) * 2)) ^ (((r) & 7) << 4))

// raw barrier: drains LDS ops only, leaves vmcnt (global/GLL prefetch) in flight
#define BARRIER() do { \
    asm volatile("s_waitcnt lgkmcnt(0)\ns_barrier" ::: "memory"); \
    __builtin_amdgcn_sched_barrier(0); \
} while (0)

__device__ __forceinline__ unsigned short f2bf(float f) {
    unsigned u = __builtin_bit_cast(unsigned, f);
    u += 0x7fffu + ((u >> 16) & 1u);
    return (unsigned short)(u >> 16);
}
__device__ __forceinline__ float bf2f(unsigned short h) {
    unsigned u = ((unsigned)h) << 16;
    return __builtin_bit_cast(float, u);
}

// async global->LDS, 16 bytes per lane (lane-contiguous dest)
__device__ __forceinline__ void gll16(const void* g, void* l) {
    __builtin_amdgcn_global_load_lds(
        (const __attribute__((address_space(1))) unsigned int*)g,
        (__attribute__((address_space(3))) unsigned int*)l,
        16, 0, 0);
}

// ---- prep: wswz = Wkv bf16 pre-permuted per 64-K tile so a LINEAR
// global_load_lds produces the XOR-swizzled LDS image the MFMA reads expect.
// Also wqT bf16[272][128], woT bf16[128][128] (k-major).
#define WKV_N (256 * KPAD)          // 114688 shorts (7 tiles x 16384)
#define WQT_N (QDIM * ODIM)         // 34816
#define WOT_N (ODIM * ODIM)         // 16384
__global__ void prep_pack(const float* __restrict__ Wkv, const float* __restrict__ Wq,
                          const float* __restrict__ Wo,
                          unsigned short* __restrict__ wswz,
                          unsigned short* __restrict__ wqT,
                          unsigned short* __restrict__ woT) {
    int idx = blockIdx.x * 256 + threadIdx.x;
    if (idx < WKV_N) {
        int tile = idx >> 14;            // 16384 shorts per K-tile
        int qb   = (idx & 16383) * 2;    // byte offset within tile's LDS image
        int row  = qb >> 7;              // W row (128 B per row)
        int x    = qb & 127;
        int f8   = (x ^ ((row & 7) << 4)) >> 4;   // inverse of the read swizzle
        int e    = (x & 15) >> 1;
        int k    = tile * KSTEP + f8 * 8 + e;
        wswz[idx] = f2bf((k < KCAT) ? Wkv[row * KCAT + k] : 0.f);
    } else if (idx < WKV_N + WQT_N) {
        int j = idx - WKV_N;
        int k = j >> 7, c = j & 127;
        wqT[j] = f2bf(Wq[c * QDIM + k]);
    } else if (idx < WKV_N + WQT_N + WOT_N) {
        int j = idx - WKV_N - WQT_N;
        int k = j >> 7, c = j & 127;
        woT[j] = f2bf(Wo[c * ODIM + k]);
    }
}

// ---- Q projection: Q[B,128] = concat(node,time) @ Wq^T + bq  (coalesced via wqT)
__global__ __launch_bounds__(256) void q_proj(
    const float* __restrict__ node_feat, const float* __restrict__ time_feat,
    const unsigned short* __restrict__ wqT, const float* __restrict__ bq,
    float* __restrict__ Qbuf) {
    __shared__ float x[8][QDIM];
    const int tid = threadIdx.x;
    const long b0 = (long)blockIdx.x * 8;
    for (int g = tid; g < 8 * QDIM; g += 256) {
        int r = g / QDIM, k = g - r * QDIM;
        x[r][k] = (k < NDIM) ? node_feat[(b0 + r) * NDIM + k]
                             : time_feat[(b0 + r) * TDIM + (k - NDIM)];
    }
    __syncthreads();
    const int c = tid & 127;
    const int rb = (tid >> 7) * 4;
    float s0 = bq[c], s1 = s0, s2 = s0, s3 = s0;
    #pragma unroll 8
    for (int k = 0; k < QDIM; k++) {
        float w = bf2f(wqT[k * 128 + c]);
        s0 += x[rb + 0][k] * w;
        s1 += x[rb + 1][k] * w;
        s2 += x[rb + 2][k] * w;
        s3 += x[rb + 3][k] * w;
    }
    Qbuf[(b0 + rb + 0) * 128 + c] = s0;
    Qbuf[(b0 + rb + 1) * 128 + c] = s1;
    Qbuf[(b0 + rb + 2) * 128 + c] = s2;
    Qbuf[(b0 + rb + 3) * 128 + c] = s3;
}

// ---- z_gemm: Z[256 rows][256] per block (8 batch rows), 1024 thr, 16 waves.
// W double-buffered via pre-swizzled GLL; A reg-staged; counted-vmcnt barriers.
__global__ __launch_bounds__(1024) void z_gemm(
    const float* __restrict__ edge_feat, const float* __restrict__ nbr_node,
    const float* __restrict__ nbr_time,
    const unsigned short* __restrict__ wswz, const float* __restrict__ bkv,
    unsigned short* __restrict__ Zws, int c0)
{
    extern __shared__ __align__(16) unsigned char smem[];
    const int tid  = threadIdx.x;
    const int lane = tid & 63;
    const int wid  = tid >> 6;           // 0..15
    const int wm   = wid >> 2;           // 0..3 : 64-row band
    const int wn   = wid & 3;            // 0..3 : 64-col band
    const int b0   = c0 + blockIdx.x * 8;

    // A staging geometry: 4 chunks/thread (256 rows x 16 float4-groups)
    int rg[4], a_koff[4], a_byte[4];
    #pragma unroll
    for (int i = 0; i < 4; i++) {
        int g = i * 1024 + tid;
        int row = g >> 4, grp = g & 15;
        rg[i] = (b0 + (row >> 5)) * NNBR + (row & 31);
        a_koff[i] = grp * 4;
        a_byte[i] = (row * 128 + grp * 8) ^ ((row & 7) << 4);
    }
    float4 areg[4];

    auto ISSUE_A = [&](int k0) {
        #pragma unroll
        for (int i = 0; i < 4; i++) {
            int k = k0 + a_koff[i];
            float4 v = make_float4(0.f, 0.f, 0.f, 0.f);
            if (k < NDIM)             v = *(const float4*)(nbr_node  + (size_t)rg[i] * NDIM + k);
            else if (k < NDIM + EDIM) v = *(const float4*)(edge_feat + (size_t)rg[i] * EDIM + (k - NDIM));
            else if (k < KCAT)        v = *(const float4*)(nbr_time  + (size_t)rg[i] * TDIM + (k - NDIM - EDIM));
            areg[i] = v;
        }
    };
    auto WRITE_A = [&]() {
        #pragma unroll
        for (int i = 0; i < 4; i++) {
            ushort4 h = make_ushort4(f2bf(areg[i].x), f2bf(areg[i].y),
                                     f2bf(areg[i].z), f2bf(areg[i].w));
            *(ushort4*)(smem + a_byte[i]) = h;
        }
    };
    auto GLL_W = [&](int t) {   // tile t -> Wbuf[t&1]; 2048 chunks / 1024 thr
        unsigned char* base = smem + ((t & 1) ? GW1 : GW0);
        #pragma unroll
        for (int j = 0; j < 2; j++) {
            int s = j * 1024 + tid;
            gll16(wswz + (size_t)t * 16384 + s * 8, base + s * 16);
        }
    };

    f32x4 acc[4][4];
    #pragma unroll
    for (int m = 0; m < 4; m++)
        #pragma unroll
        for (int n = 0; n < 4; n++) acc[m][n] = (f32x4){0.f, 0.f, 0.f, 0.f};

    auto COMPUTE = [&](const unsigned char* wbase) {
        #pragma unroll
        for (int kk = 0; kk < 2; kk++) {
            const int kb = kk * 64 + (lane >> 4) * 16;
            bf16x8 af[4], bfr[4];
            #pragma unroll
            for (int m = 0; m < 4; m++) {
                int row = wm * 64 + m * 16 + (lane & 15);
                int byte = (row * 128 + kb) ^ ((row & 7) << 4);
                af[m] = __builtin_bit_cast(bf16x8, *(const short8*)(smem + byte));
            }
            #pragma unroll
            for (int n = 0; n < 4; n++) {
                int row = wn * 64 + n * 16 + (lane & 15);   // W row = Z column
                int byte = (row * 128 + kb) ^ ((row & 7) << 4);
                bfr[n] = __builtin_bit_cast(bf16x8, *(const short8*)(wbase + byte));
            }
            #pragma unroll
            for (int m = 0; m < 4; m++)
                #pragma unroll
                for (int n = 0; n < 4; n++)
                    acc[m][n] = __builtin_amdgcn_mfma_f32_16x16x32_bf16(af[m], bfr[n], acc[m][n], 0, 0, 0);
        }
    };

    // prologue: A(0) issued before W(0) so WRITE_A's counted wait leaves W flying
    ISSUE_A(0);
    GLL_W(0);
    WRITE_A();                         // counted vmcnt: waits A(0), leaves W(0)
    GLL_W(1);
    asm volatile("s_waitcnt vmcnt(2)" ::: "memory");   // W(0) landed, W(1) flies
    __builtin_amdgcn_sched_barrier(0);
    BARRIER();

    #pragma unroll
    for (int ks = 0; ks < NKS; ks++) {
        if (ks < NKS - 1) ISSUE_A((ks + 1) * KSTEP);   // flies under compute
        COMPUTE(smem + ((ks & 1) ? GW1 : GW0));
        BARRIER();                                     // Abuf + Wbuf[ks&1] free
        if (ks < NKS - 1) {
            if (ks < NKS - 2) GLL_W(ks + 2);           // into just-freed buf
            __builtin_amdgcn_sched_barrier(0);
            WRITE_A();                                 // counted wait (A older than GLL)
            if (ks < NKS - 2) {
                asm volatile("s_waitcnt vmcnt(2)" ::: "memory");  // W(ks+1) landed
            } else {
                asm volatile("s_waitcnt vmcnt(0)" ::: "memory");
            }
            __builtin_amdgcn_sched_barrier(0);
            BARRIER();
        }
    }
    __syncthreads();

    // ---- epilogue: acc(+bkv) -> LDS [128][512B] swizzled -> coalesced global Z
    float bk[4];
    #pragma unroll
    for (int n = 0; n < 4; n++) bk[n] = bkv[wn * 64 + n * 16 + (lane & 15)];
    #pragma unroll
    for (int h = 0; h < 2; h++) {
        if ((wm >> 1) == h) {
            #pragma unroll
            for (int n = 0; n < 4; n++) {
                int col = wn * 64 + n * 16 + (lane & 15);
                #pragma unroll
                for (int m = 0; m < 4; m++) {
                    #pragma unroll
                    for (int j = 0; j < 4; j++) {
                        int lrow = (wm & 1) * 64 + m * 16 + (lane >> 4) * 4 + j;
                        *(unsigned short*)(smem + ZB(lrow, col)) =
                            f2bf(acc[m][n][j] + bk[n]);
                    }
                }
            }
        }
        __syncthreads();
        size_t gb = ((size_t)blockIdx.x * 256 + h * 128) * ZDIM;  // shorts
        #pragma unroll
        for (int i = 0; i < 4; i++) {
            int g = i * 1024 + tid;          // 4096 x 16B chunks
            int lrow = g >> 5;
            int lb = (g * 16) ^ ((lrow & 7) << 4);
            *(uint4*)(Zws + gb + (size_t)g * 8) = *(const uint4*)(smem + lb);
        }
        __syncthreads();
    }
}

// ---- attn_tail: 4 batch rows per 512-thr block; streams Z, R4-proven phases
__global__ __launch_bounds__(512) void attn_tail(
    const unsigned short* __restrict__ Zws, const int* __restrict__ nbr_mask,
    const float* __restrict__ Qbuf,
    const unsigned short* __restrict__ woT, const float* __restrict__ bo,
    const float* __restrict__ gamma, const float* __restrict__ beta,
    float* __restrict__ out, int c0)
{
    extern __shared__ __align__(16) unsigned char zsm[];
    float* qres  = (float*)(zsm + AT_Q);   // [4][128]
    float* Pband = (float*)(zsm + AT_P);   // [4][2][32]
    float* Obuf  = (float*)(zsm + AT_O);   // [4][128]
    float* red   = (float*)(zsm + AT_R);   // [8][2]

    const int tid  = threadIdx.x;
    const int lane = tid & 63;
    const int wid  = tid >> 6;
    const int b0   = c0 + blockIdx.x * 4;

    // stage Q rows (coalesced)
    {
        int b = tid >> 7, c = tid & 127;
        qres[b * ODIM + c] = Qbuf[(long)(b0 + b) * ODIM + c];
    }
    // stage Z: 128 rows x 512B, global linear -> LDS ZB-swizzled
    const unsigned short* zg = Zws + (size_t)blockIdx.x * 4 * NNBR * ZDIM;
    #pragma unroll
    for (int i = 0; i < 8; i++) {
        int g = i * 512 + tid;               // 4096 x 16B chunks
        int row = g >> 5;
        int lb = (g * 16) ^ ((row & 7) << 4);
        *(uint4*)(zsm + lb) = *(const uint4*)(zg + (size_t)g * 8);
    }
    __syncthreads();

    // ---- scores + softmax: waves 0..7 -> (b=wid>>1, h=wid&1); lane pair per n2
    {
        int bl = wid >> 1, h = wid & 1;
        int n2 = lane >> 1, half = lane & 1;
        int np = h * 16 + (n2 >> 1);                  // Z row (mixed reshape)
        int rowZ = bl * NNBR + np;
        int cb = (n2 & 1) * 64 + half * 32;           // Z col base (K part)
        const float* q = qres + bl * ODIM + h * 64 + half * 32;
        float s = 0.f;
        #pragma unroll
        for (int j = 0; j < 4; j++) {
            short8 z8 = *(const short8*)(zsm + ZB(rowZ, cb + j * 8));
            #pragma unroll
            for (int e = 0; e < 8; e++)
                s += q[j * 8 + e] * bf2f((unsigned short)z8[e]);
        }
        s += __shfl_xor(s, 1);
        s *= 0.125f;  // HEAD_DIM^-0.5
        if (nbr_mask[(long)(b0 + bl) * NNBR + n2] == 0) s = -1e10f;
        float mx = s;
        #pragma unroll
        for (int off = 1; off < 64; off <<= 1) mx = fmaxf(mx, __shfl_xor(mx, off));
        float e = __expf(s - mx);
        float sum = e;
        #pragma unroll
        for (int off = 1; off < 64; off <<= 1) sum += __shfl_xor(sum, off);
        float p = e * 2.f / sum;   // each n2 counted twice in sum
        if (half == 0) Pband[(bl * 2 + h) * NNBR + n2] = p;
    }
    __syncthreads();

    // ---- O = P @ V : one thread per (b, h*64+d)
    {
        int b = tid >> 7, c = tid & 127, h = c >> 6, d = c & 63;
        const float* P = Pband + (b * 2 + h) * NNBR;
        float s = 0.f;
        #pragma unroll
        for (int n2 = 0; n2 < NNBR; n2++) {
            int np = h * 16 + (n2 >> 1);
            int col = ODIM + (n2 & 1) * 64 + d;       // V part
            s += P[n2] * bf2f(*(const unsigned short*)(zsm + ZB(b * NNBR + np, col)));
        }
        Obuf[b * ODIM + c] = s;
    }
    __syncthreads();

    // ---- out proj (coalesced via woT) + LayerNorm
    {
        int b = tid >> 7, c = tid & 127;
        float s = bo[c];
        const float* ob = Obuf + b * ODIM;
        #pragma unroll 8
        for (int k = 0; k < ODIM; k++)
            s += ob[k] * bf2f(woT[k * 128 + c]);
        float s1 = s, s2 = s * s;
        #pragma unroll
        for (int off = 1; off < 64; off <<= 1) {
            s1 += __shfl_xor(s1, off);
            s2 += __shfl_xor(s2, off);
        }
        if (lane == 0) { red[wid * 2] = s1; red[wid * 2 + 1] = s2; }
        __syncthreads();
        float t1 = red[b * 4 + 0] + red[b * 4 + 2];
        float t2 = red[b * 4 + 1] + red[b * 4 + 3];
        float mu  = t1 * (1.f / 128.f);
        float var = t2 * (1.f / 128.f) - mu * mu;
        float inv = rsqrtf(var + LN_EPS);
        out[(long)(b0 + b) * ODIM + c] = (s - mu) * inv * gamma[c] + beta[c];
    }
}

extern "C" void kernel_launch(void* const* d_in, const int* in_sizes, int n_in,
                              void* d_out, int out_size, void* d_ws, size_t ws_size,
                              hipStream_t stream) {
    const float* node_feat = (const float*)d_in[0];
    const float* time_feat = (const float*)d_in[1];
    const float* edge_feat = (const float*)d_in[2];
    const float* nbr_node  = (const float*)d_in[3];
    const float* nbr_time  = (const float*)d_in[4];
    const int*   nbr_mask  = (const int*)d_in[5];
    const float* Wq   = (const float*)d_in[6];
    const float* bq   = (const float*)d_in[7];
    const float* Wkv  = (const float*)d_in[8];
    const float* bkv  = (const float*)d_in[9];
    const float* Wo   = (const float*)d_in[10];
    const float* bo   = (const float*)d_in[11];
    const float* gma  = (const float*)d_in[12];
    const float* bta  = (const float*)d_in[13];
    float* out = (float*)d_out;

    const int B = in_sizes[0] / NDIM;  // 8192

    // workspace: [Qbuf B*128 f32][wswz][wqT][woT][Zws ...]
    char* ws = (char*)d_ws;
    float* Qbuf = (float*)ws;
    size_t off = (size_t)B * ODIM * 4;
    unsigned short* wswz = (unsigned short*)(ws + off);
    unsigned short* wqT  = wswz + WKV_N;
    unsigned short* woT  = wqT + WQT_N;
    size_t fixed = off + 2 * (size_t)(WKV_N + WQT_N + WOT_N);
    fixed = (fixed + 255) & ~(size_t)255;
    unsigned short* Zws = (unsigned short*)(ws + fixed);

    const size_t row_bytes = (size_t)NNBR * ZDIM * 2;   // 16 KB per batch row
    size_t zavail = (ws_size > fixed) ? (ws_size - fixed) : 0;
    int chunk_b;
    if (zavail >= (size_t)B * row_bytes) chunk_b = B;
    else {
        chunk_b = (int)(zavail / row_bytes) & ~7;
        if (chunk_b < 8) chunk_b = 8;   // minimal functional chunk
    }

    hipFuncSetAttribute((const void*)z_gemm,
                        hipFuncAttributeMaxDynamicSharedMemorySize, GEMM_LDS);
    hipFuncSetAttribute((const void*)attn_tail,
                        hipFuncAttributeMaxDynamicSharedMemorySize, AT_LDS);

    const int prep_total = WKV_N + WQT_N + WOT_N;
    prep_pack<<<dim3((prep_total + 255) / 256), dim3(256), 0, stream>>>(
        Wkv, Wq, Wo, wswz, wqT, woT);
    q_proj<<<dim3(B / 8), dim3(256), 0, stream>>>(node_feat, time_feat, wqT, bq, Qbuf);

    for (int c0 = 0; c0 < B; c0 += chunk_b) {
        int cb = (B - c0 < chunk_b) ? (B - c0) : chunk_b;
        z_gemm<<<dim3(cb / 8), dim3(1024), GEMM_LDS, stream>>>(
            edge_feat, nbr_node, nbr_time, wswz, bkv, Zws, c0);
        attn_tail<<<dim3(cb / 4), dim3(512), AT_LDS, stream>>>(
            Zws, nbr_mask, Qbuf, woT, bo, gma, bta, out, c0);
    }
}

// Round 11
// 222.698 us; speedup vs baseline: 1.8391x; 1.8391x over previous
//
#include <hip/hip_runtime.h>
#include <hip/hip_bf16.h>

typedef __attribute__((ext_vector_type(4))) float f32x4;
typedef __attribute__((ext_vector_type(8))) short short8;
typedef __attribute__((ext_vector_type(8))) __bf16 bf16x8;

#define NDIM 172
#define EDIM 172
#define TDIM 100
#define KCAT 444   // 172+172+100
#define KPAD 448
#define QDIM 272   // 172+100
#define ODIM 128
#define ZDIM 256
#define NNBR 32
#define BPB 4      // batch rows per block (M = 128)
#define KSTEP 64
#define NKS (KPAD / KSTEP)   // 7
#define LN_EPS 1e-5f

// ---- LDS layout (dynamic, 1 block/CU) ----
// A0 [0,32K) A1 [32K,64K): fp32 [128 rows][256B], grp-XOR swizzled
// W0 [64K,96K) W1 [96K,128K): bf16 [256 rows][128B], pre-swizzled via wswz
// Z bf16 [128][256] ZB-swizzled unions into [0,64K) for the tail
#define A0_OFF 0
#define A1_OFF 32768
#define W0_OFF 65536
#define W1_OFF 98304
#define T_QRES 131072
#define T_PBAND 133120
#define T_OBUF 134144
#define T_RED 136192
#define SMEM_BYTES 136256

// Z byte offset with XOR bank-swizzle (row stride 512 B)
#define ZB(r,c) ((((r) * 512) + ((c) * 2)) ^ (((r) & 7) << 4))

// raw barrier: drains LDS ops only, leaves vmcnt (GLL prefetch) in flight
#define BARRIER() do { \
    asm volatile("s_waitcnt lgkmcnt(0)\ns_barrier" ::: "memory"); \
    __builtin_amdgcn_sched_barrier(0); \
} while (0)
#define VMCNT(n) do { \
    asm volatile("s_waitcnt vmcnt(" #n ")" ::: "memory"); \
    __builtin_amdgcn_sched_barrier(0); \
} while (0)

__device__ __forceinline__ unsigned short f2bf(float f) {
    unsigned u = __builtin_bit_cast(unsigned, f);
    u += 0x7fffu + ((u >> 16) & 1u);
    return (unsigned short)(u >> 16);
}
__device__ __forceinline__ float bf2f(unsigned short h) {
    unsigned u = ((unsigned)h) << 16;
    return __builtin_bit_cast(float, u);
}
__device__ __forceinline__ bf16x8 cvt8(float4 a, float4 b) {
    bf16x8 r;
    r[0] = (__bf16)a.x; r[1] = (__bf16)a.y; r[2] = (__bf16)a.z; r[3] = (__bf16)a.w;
    r[4] = (__bf16)b.x; r[5] = (__bf16)b.y; r[6] = (__bf16)b.z; r[7] = (__bf16)b.w;
    return r;
}

// async global->LDS, 16 bytes per lane (lane-linear dest)
__device__ __forceinline__ void gll16(const void* g, void* l) {
    __builtin_amdgcn_global_load_lds(
        (const __attribute__((address_space(1))) unsigned int*)g,
        (__attribute__((address_space(3))) unsigned int*)l,
        16, 0, 0);
}

// ---- prep: wswz = Wkv bf16 pre-permuted per 64-K tile (linear GLL -> swizzled
// LDS image). Also wqT bf16[272][128], woT bf16[128][128] (k-major).
#define WKV_N (256 * KPAD)          // 114688 shorts (7 tiles x 16384)
#define WQT_N (QDIM * ODIM)         // 34816
#define WOT_N (ODIM * ODIM)         // 16384
__global__ void prep_pack(const float* __restrict__ Wkv, const float* __restrict__ Wq,
                          const float* __restrict__ Wo,
                          unsigned short* __restrict__ wswz,
                          unsigned short* __restrict__ wqT,
                          unsigned short* __restrict__ woT) {
    int idx = blockIdx.x * 256 + threadIdx.x;
    if (idx < WKV_N) {
        int tile = idx >> 14;            // 16384 shorts per K-tile
        int qb   = (idx & 16383) * 2;    // byte offset within tile's LDS image
        int row  = qb >> 7;              // W row (128 B per row)
        int x    = qb & 127;
        int f8   = (x ^ ((row & 7) << 4)) >> 4;   // inverse of the read swizzle
        int e    = (x & 15) >> 1;
        int k    = tile * KSTEP + f8 * 8 + e;
        wswz[idx] = f2bf((k < KCAT) ? Wkv[row * KCAT + k] : 0.f);
    } else if (idx < WKV_N + WQT_N) {
        int j = idx - WKV_N;
        int k = j >> 7, c = j & 127;
        wqT[j] = f2bf(Wq[c * QDIM + k]);
    } else if (idx < WKV_N + WQT_N + WOT_N) {
        int j = idx - WKV_N - WQT_N;
        int k = j >> 7, c = j & 127;
        woT[j] = f2bf(Wo[c * ODIM + k]);
    }
}

// ---- Q projection: Q[B,128] = concat(node,time) @ Wq^T + bq  (coalesced via wqT)
__global__ __launch_bounds__(256) void q_proj(
    const float* __restrict__ node_feat, const float* __restrict__ time_feat,
    const unsigned short* __restrict__ wqT, const float* __restrict__ bq,
    float* __restrict__ Qbuf) {
    __shared__ float x[8][QDIM];
    const int tid = threadIdx.x;
    const long b0 = (long)blockIdx.x * 8;
    for (int g = tid; g < 8 * QDIM; g += 256) {
        int r = g / QDIM, k = g - r * QDIM;
        x[r][k] = (k < NDIM) ? node_feat[(b0 + r) * NDIM + k]
                             : time_feat[(b0 + r) * TDIM + (k - NDIM)];
    }
    __syncthreads();
    const int c = tid & 127;
    const int rb = (tid >> 7) * 4;
    float s0 = bq[c], s1 = s0, s2 = s0, s3 = s0;
    #pragma unroll 8
    for (int k = 0; k < QDIM; k++) {
        float w = bf2f(wqT[k * 128 + c]);
        s0 += x[rb + 0][k] * w;
        s1 += x[rb + 1][k] * w;
        s2 += x[rb + 2][k] * w;
        s3 += x[rb + 3][k] * w;
    }
    Qbuf[(b0 + rb + 0) * 128 + c] = s0;
    Qbuf[(b0 + rb + 1) * 128 + c] = s1;
    Qbuf[(b0 + rb + 2) * 128 + c] = s2;
    Qbuf[(b0 + rb + 3) * 128 + c] = s3;
}

// ---- fused: M=128 tile, 1024 thr (16 waves 4x4), all staging via GLL.
// __launch_bounds__(1024,4): 1 block/CU, VGPR cap 128 (acc 32 + ~70 addr).
__global__ __launch_bounds__(1024, 4) void ta_fused(
    const float* __restrict__ edge_feat, const float* __restrict__ nbr_node,
    const float* __restrict__ nbr_time, const int* __restrict__ nbr_mask,
    const float* __restrict__ Qbuf,
    const unsigned short* __restrict__ wswz, const float* __restrict__ bkv,
    const unsigned short* __restrict__ woT, const float* __restrict__ bo,
    const float* __restrict__ gamma, const float* __restrict__ beta,
    float* __restrict__ out)
{
    extern __shared__ __align__(16) unsigned char smem[];
    float* qres  = (float*)(smem + T_QRES);   // [4][128]
    float* Pband = (float*)(smem + T_PBAND);  // [4][2][32]
    float* Obuf  = (float*)(smem + T_OBUF);   // [4][128]
    float* red   = (float*)(smem + T_RED);    // [8][2]

    const int tid  = threadIdx.x;
    const int lane = tid & 63;
    const int wid  = tid >> 6;           // 0..15
    const int wm   = wid >> 2;           // 0..3 : 32-row band
    const int wn   = wid & 3;            // 0..3 : 64-col band
    const int b0   = blockIdx.x * BPB;

    // ---- GLL staging lambdas (no destination registers -> un-sinkable)
    auto GLL_A = [&](int t) {            // K-tile t -> Abuf[t&1], fp32 swizzled
        unsigned char* base = smem + ((t & 1) ? A1_OFF : A0_OFF);
        const int k0 = t * KSTEP;
        #pragma unroll
        for (int j = 0; j < 2; j++) {
            int g = (wid * 2 + j) * 64 + lane;   // 16B chunk [0,2048)
            int row = g >> 4, grp = g & 15;
            int fidx = k0 + ((grp ^ (row & 7)) << 2);
            long rg = (long)(b0 + (row >> 5)) * NNBR + (row & 31);
            const float* src;
            if (fidx < NDIM)             src = nbr_node + rg * NDIM + fidx;
            else if (fidx < NDIM + EDIM) src = edge_feat + rg * EDIM + (fidx - NDIM);
            else {                       // time part; pad k>=444 clamps in-bounds,
                int f = fidx - NDIM - EDIM;       // finite garbage x W=0 -> 0
                src = nbr_time + rg * TDIM + (f > 96 ? 96 : f);
            }
            gll16(src, base + g * 16);
        }
    };
    auto GLL_W = [&](int t) {            // K-tile t -> Wbuf[t&1], bf16 pre-swz
        unsigned char* base = smem + ((t & 1) ? W1_OFF : W0_OFF);
        #pragma unroll
        for (int j = 0; j < 2; j++) {
            int s = (wid * 2 + j) * 64 + lane;   // 16B chunk [0,2048)
            gll16(wswz + (size_t)t * 16384 + s * 8, base + s * 16);
        }
    };

    f32x4 acc[2][4];
    #pragma unroll
    for (int m = 0; m < 2; m++)
        #pragma unroll
        for (int n = 0; n < 4; n++) acc[m][n] = (f32x4){0.f, 0.f, 0.f, 0.f};

    auto COMPUTE = [&](int t) {
        const unsigned char* abase = smem + ((t & 1) ? A1_OFF : A0_OFF);
        const unsigned char* wbase = smem + ((t & 1) ? W1_OFF : W0_OFF);
        #pragma unroll
        for (int kk = 0; kk < 2; kk++) {
            bf16x8 af[2], bfr[4];
            #pragma unroll
            for (int m = 0; m < 2; m++) {
                int row = wm * 32 + m * 16 + (lane & 15);
                int gA = kk * 8 + ((lane >> 4) << 1);
                float4 lo = *(const float4*)(abase + row * 256 + ((gA ^ (row & 7)) << 4));
                float4 hi = *(const float4*)(abase + row * 256 + (((gA + 1) ^ (row & 7)) << 4));
                af[m] = cvt8(lo, hi);
            }
            const int kb = kk * 64 + (lane >> 4) * 16;
            #pragma unroll
            for (int n = 0; n < 4; n++) {
                int row = wn * 64 + n * 16 + (lane & 15);   // W row = Z column
                bfr[n] = __builtin_bit_cast(bf16x8,
                    *(const short8*)(wbase + ((row * 128 + kb) ^ ((row & 7) << 4))));
            }
            #pragma unroll
            for (int m = 0; m < 2; m++)
                #pragma unroll
                for (int n = 0; n < 4; n++)
                    acc[m][n] = __builtin_amdgcn_mfma_f32_16x16x32_bf16(af[m], bfr[n], acc[m][n], 0, 0, 0);
        }
    };

    // ---- prologue: tiles 0,1 in flight; wait tile 0 only (counted)
    GLL_A(0); GLL_W(0);                  // 4 ops/lane
    GLL_A(1); GLL_W(1);                  // 8 ops/lane
    VMCNT(4);                            // tile 0 landed, tile 1 flying
    BARRIER();

    #pragma unroll
    for (int t = 0; t < NKS; t++) {
        COMPUTE(t);
        if (t < NKS - 1) {
            BARRIER();                   // buf t free for all waves
            if (t + 2 < NKS) {
                GLL_A(t + 2); GLL_W(t + 2);   // into just-freed buf
                VMCNT(4);                // tile t+1 landed, t+2 flying
            } else {
                VMCNT(0);                // last prefetched tile drains
            }
            BARRIER();
        }
    }
    __syncthreads();

    // ---- stage Q rows + dump Z (+bkv) into [0,64K) (ZB swizzle)
    if (tid < BPB * ODIM) {
        int b = tid >> 7, c = tid & 127;
        qres[b * ODIM + c] = Qbuf[(long)(b0 + b) * ODIM + c];
    }
    #pragma unroll
    for (int n = 0; n < 4; n++) {
        int col = wn * 64 + n * 16 + (lane & 15);
        float bk = bkv[col];
        #pragma unroll
        for (int m = 0; m < 2; m++) {
            #pragma unroll
            for (int j = 0; j < 4; j++) {
                int row = wm * 32 + m * 16 + (lane >> 4) * 4 + j;
                *(unsigned short*)(smem + ZB(row, col)) =
                    __builtin_bit_cast(unsigned short, (__bf16)(acc[m][n][j] + bk));
            }
        }
    }
    __syncthreads();

    // ---- scores + softmax: waves 0..7 -> (b=wid>>1, h=wid&1); lane pair per n2
    if (wid < 2 * BPB) {
        int bl = wid >> 1, h = wid & 1;
        int n2 = lane >> 1, half = lane & 1;
        int np = h * 16 + (n2 >> 1);                  // Z row (mixed reshape)
        int rowZ = bl * NNBR + np;
        int cb = (n2 & 1) * 64 + half * 32;           // Z col base (K part)
        const float* q = qres + bl * ODIM + h * 64 + half * 32;
        float s = 0.f;
        #pragma unroll
        for (int j = 0; j < 4; j++) {
            short8 z8 = *(const short8*)(smem + ZB(rowZ, cb + j * 8));
            #pragma unroll
            for (int e = 0; e < 8; e++)
                s += q[j * 8 + e] * bf2f((unsigned short)z8[e]);
        }
        s += __shfl_xor(s, 1);
        s *= 0.125f;  // HEAD_DIM^-0.5
        if (nbr_mask[(long)(b0 + bl) * NNBR + n2] == 0) s = -1e10f;
        float mx = s;
        #pragma unroll
        for (int off = 1; off < 64; off <<= 1) mx = fmaxf(mx, __shfl_xor(mx, off));
        float e = __expf(s - mx);
        float sum = e;
        #pragma unroll
        for (int off = 1; off < 64; off <<= 1) sum += __shfl_xor(sum, off);
        float p = e * 2.f / sum;   // each n2 counted twice in sum
        if (half == 0) Pband[(bl * 2 + h) * NNBR + n2] = p;
    }
    __syncthreads();

    // ---- O = P @ V : one thread per (b, h*64+d)
    if (tid < BPB * ODIM) {
        int b = tid >> 7, c = tid & 127, h = c >> 6, d = c & 63;
        const float* P = Pband + (b * 2 + h) * NNBR;
        float s = 0.f;
        #pragma unroll
        for (int n2 = 0; n2 < NNBR; n2++) {
            int np = h * 16 + (n2 >> 1);
            int col = ODIM + (n2 & 1) * 64 + d;       // V part
            s += P[n2] * bf2f(*(const unsigned short*)(smem + ZB(b * NNBR + np, col)));
        }
        Obuf[b * ODIM + c] = s;
    }
    __syncthreads();

    // ---- out proj (coalesced via woT) + LayerNorm
    {
        int b = tid >> 7, c = tid & 127;
        float s = 0.f;
        if (tid < BPB * ODIM) {
            s = bo[c];
            const float* ob = Obuf + b * ODIM;
            #pragma unroll 8
            for (int k = 0; k < ODIM; k++)
                s += ob[k] * bf2f(woT[k * 128 + c]);
        }
        float s1 = s, s2 = s * s;
        #pragma unroll
        for (int off = 1; off < 64; off <<= 1) {
            s1 += __shfl_xor(s1, off);
            s2 += __shfl_xor(s2, off);
        }
        if (wid < 2 * BPB && lane == 0) { red[wid * 2] = s1; red[wid * 2 + 1] = s2; }
        __syncthreads();
        if (tid < BPB * ODIM) {
            float t1 = red[b * 4 + 0] + red[b * 4 + 2];
            float t2 = red[b * 4 + 1] + red[b * 4 + 3];
            float mu  = t1 * (1.f / 128.f);
            float var = t2 * (1.f / 128.f) - mu * mu;
            float inv = rsqrtf(var + LN_EPS);
            out[(long)(b0 + b) * ODIM + c] = (s - mu) * inv * gamma[c] + beta[c];
        }
    }
}

extern "C" void kernel_launch(void* const* d_in, const int* in_sizes, int n_in,
                              void* d_out, int out_size, void* d_ws, size_t ws_size,
                              hipStream_t stream) {
    const float* node_feat = (const float*)d_in[0];
    const float* time_feat = (const float*)d_in[1];
    const float* edge_feat = (const float*)d_in[2];
    const float* nbr_node  = (const float*)d_in[3];
    const float* nbr_time  = (const float*)d_in[4];
    const int*   nbr_mask  = (const int*)d_in[5];
    const float* Wq   = (const float*)d_in[6];
    const float* bq   = (const float*)d_in[7];
    const float* Wkv  = (const float*)d_in[8];
    const float* bkv  = (const float*)d_in[9];
    const float* Wo   = (const float*)d_in[10];
    const float* bo   = (const float*)d_in[11];
    const float* gma  = (const float*)d_in[12];
    const float* bta  = (const float*)d_in[13];
    float* out = (float*)d_out;

    const int B = in_sizes[0] / NDIM;  // 8192

    // workspace layout
    char* ws = (char*)d_ws;
    float* Qbuf = (float*)ws;                                   // B*128*4 = 4 MB
    unsigned short* wswz = (unsigned short*)(ws + (size_t)B * ODIM * 4);
    unsigned short* wqT  = wswz + WKV_N;
    unsigned short* woT  = wqT + WQT_N;

    hipFuncSetAttribute((const void*)ta_fused,
                        hipFuncAttributeMaxDynamicSharedMemorySize, SMEM_BYTES);

    const int prep_total = WKV_N + WQT_N + WOT_N;
    prep_pack<<<dim3((prep_total + 255) / 256), dim3(256), 0, stream>>>(
        Wkv, Wq, Wo, wswz, wqT, woT);
    q_proj<<<dim3(B / 8), dim3(256), 0, stream>>>(node_feat, time_feat, wqT, bq, Qbuf);
    ta_fused<<<dim3(B / BPB), dim3(1024), SMEM_BYTES, stream>>>(
        edge_feat, nbr_node, nbr_time, nbr_mask, Qbuf,
        wswz, bkv, woT, bo, gma, bta, out);
}

// Round 12
// 179.315 us; speedup vs baseline: 2.2840x; 1.2419x over previous
//
#include <hip/hip_runtime.h>
#include <hip/hip_bf16.h>

typedef __attribute__((ext_vector_type(4))) float f32x4;
typedef __attribute__((ext_vector_type(8))) short short8;
typedef __attribute__((ext_vector_type(8))) __bf16 bf16x8;

#define NDIM 172
#define EDIM 172
#define TDIM 100
#define KCAT 444   // 172+172+100
#define QDIM 272   // 172+100
#define ODIM 128
#define ZDIM 256
#define NNBR 32
#define NPH 14     // K=32 phases (448 padded)
#define NT 7       // K=64 tiles
#define RPB 8      // batch rows per block
#define LN_EPS 1e-5f

// ---- LDS map (dynamic, ~80 KB, 1 block/CU) ----
#define Z_OFF    0         // Z bf16 [128][256] ZB-swizzled (4-row tail groups)
#define A_OFF    65536     // A exchange: 2 slots x 4 KB bf16 [32][64] swizzled
#define QRES_OFF 73728     // [8][128] f32
#define MASK_OFF 77824     // [8][32] int
#define PB_OFF   78848     // [4][2][32] f32
#define OB_OFF   79872     // [4][128] f32
#define RED_OFF  81920     // [8][2] f32
#define SMEM_BYTES 81984

#define ZB(r,c) ((((r) * 512) + ((c) * 2)) ^ (((r) & 7) << 4))

// lgkm-only barrier: vmcnt (the deep A-load pipeline) stays in flight
#define BARRIER() do { \
    asm volatile("s_waitcnt lgkmcnt(0)\ns_barrier" ::: "memory"); \
    __builtin_amdgcn_sched_barrier(0); \
} while (0)

__device__ __forceinline__ unsigned short f2bf(float f) {
    unsigned u = __builtin_bit_cast(unsigned, f);
    u += 0x7fffu + ((u >> 16) & 1u);
    return (unsigned short)(u >> 16);
}
__device__ __forceinline__ float bf2f(unsigned short h) {
    unsigned u = ((unsigned)h) << 16;
    return __builtin_bit_cast(float, u);
}
__device__ __forceinline__ unsigned short bfb(float f) {
    return __builtin_bit_cast(unsigned short, (__bf16)f);
}

// ---- prep: wfrag = Wkv bf16 in MFMA B-fragment order (R7 layout):
// [phase 0..13][n16 0..15][lane 0..63][8]; row=n16*16+(l&15), k=phase*32+(l>>4)*8+e
#define WFRAG_N (NPH * 8192)        // 114688 shorts
#define WQT_N (QDIM * ODIM)         // 34816
#define WOT_N (ODIM * ODIM)         // 16384
__global__ void prep_pack(const float* __restrict__ Wkv, const float* __restrict__ Wq,
                          const float* __restrict__ Wo,
                          unsigned short* __restrict__ wfrag,
                          unsigned short* __restrict__ wqT,
                          unsigned short* __restrict__ woT) {
    int idx = blockIdx.x * 256 + threadIdx.x;
    if (idx < WFRAG_N) {
        int phase = idx >> 13;
        int r = idx & 8191;
        int n16 = r >> 9;
        int q = r & 511;
        int l = q >> 3, e = q & 7;
        int row = n16 * 16 + (l & 15);
        int k = phase * 32 + ((l >> 4) << 3) + e;
        wfrag[idx] = f2bf(k < KCAT ? Wkv[row * KCAT + k] : 0.f);
    } else if (idx < WFRAG_N + WQT_N) {
        int j = idx - WFRAG_N;
        int k = j >> 7, c = j & 127;
        wqT[j] = f2bf(Wq[c * QDIM + k]);
    } else if (idx < WFRAG_N + WQT_N + WOT_N) {
        int j = idx - WFRAG_N - WQT_N;
        int k = j >> 7, c = j & 127;
        woT[j] = f2bf(Wo[c * ODIM + k]);
    }
}

// ---- Q projection (unchanged, proven)
__global__ __launch_bounds__(256) void q_proj(
    const float* __restrict__ node_feat, const float* __restrict__ time_feat,
    const unsigned short* __restrict__ wqT, const float* __restrict__ bq,
    float* __restrict__ Qbuf) {
    __shared__ float x[8][QDIM];
    const int tid = threadIdx.x;
    const long b0 = (long)blockIdx.x * 8;
    for (int g = tid; g < 8 * QDIM; g += 256) {
        int r = g / QDIM, k = g - r * QDIM;
        x[r][k] = (k < NDIM) ? node_feat[(b0 + r) * NDIM + k]
                             : time_feat[(b0 + r) * TDIM + (k - NDIM)];
    }
    __syncthreads();
    const int c = tid & 127;
    const int rb = (tid >> 7) * 4;
    float s0 = bq[c], s1 = s0, s2 = s0, s3 = s0;
    #pragma unroll 8
    for (int k = 0; k < QDIM; k++) {
        float w = bf2f(wqT[k * 128 + c]);
        s0 += x[rb + 0][k] * w;
        s1 += x[rb + 1][k] * w;
        s2 += x[rb + 2][k] * w;
        s3 += x[rb + 3][k] * w;
    }
    Qbuf[(b0 + rb + 0) * 128 + c] = s0;
    Qbuf[(b0 + rb + 1) * 128 + c] = s1;
    Qbuf[(b0 + rb + 2) * 128 + c] = s2;
    Qbuf[(b0 + rb + 3) * 128 + c] = s3;
}

// ---- fused: W in registers (112 VGPR/wave), A reg-pipelined 7 tiles deep,
// tiny LDS exchange, lgkm-only barriers. 512 thr, 2 waves/SIMD by design.
__global__ __launch_bounds__(512, 2) void ta_fused(
    const float* __restrict__ edge_feat, const float* __restrict__ nbr_node,
    const float* __restrict__ nbr_time, const int* __restrict__ nbr_mask,
    const float* __restrict__ Qbuf,
    const unsigned short* __restrict__ wfrag, const float* __restrict__ bkv,
    const unsigned short* __restrict__ woT, const float* __restrict__ bo,
    const float* __restrict__ gamma, const float* __restrict__ beta,
    float* __restrict__ out)
{
    extern __shared__ __align__(16) unsigned char smem[];
    float* qresL = (float*)(smem + QRES_OFF);
    int*   maskL = (int*)(smem + MASK_OFF);
    float* Pband = (float*)(smem + PB_OFF);
    float* Obuf  = (float*)(smem + OB_OFF);
    float* red   = (float*)(smem + RED_OFF);

    const int tid  = threadIdx.x;
    const int lane = tid & 63;
    const int wid  = tid >> 6;          // 0..7 = 32-col band
    const int b0   = blockIdx.x * RPB;

    // ---- stage masks + Q rows for the block's 8 batch rows
    if (tid < RPB * NNBR) maskL[tid] = nbr_mask[(long)b0 * NNBR + tid];
    qresL[tid]       = Qbuf[(long)b0 * ODIM + tid];
    qresL[tid + 512] = Qbuf[(long)b0 * ODIM + tid + 512];
    __syncthreads();   // one-time full drain, nothing deep in flight yet

    // ---- W fragments into registers (read-only, literal indices only)
    bf16x8 Wr[2 * NPH];
    #pragma unroll
    for (int p = 0; p < NPH; p++)
        #pragma unroll
        for (int j = 0; j < 2; j++)
            Wr[p * 2 + j] = __builtin_bit_cast(bf16x8,
                *(const short8*)(wfrag + ((size_t)(p * 16 + wid * 2 + j) * 512 + lane * 8)));
    const float bk0 = bkv[wid * 32 + (lane & 15)];
    const float bk1 = bkv[wid * 32 + 16 + (lane & 15)];

    // ---- per-thread A geometry: thread = (rowA 0..31, kgrp 0..15)
    const int rowA  = tid >> 4;
    const int kgrp4 = (tid & 15) * 4;
    const int awb   = ((rowA * 128 + (tid & 15) * 8) ^ ((rowA & 7) << 4));

    auto loadA = [&](int riX, int t) -> float4 {
        int k = t * 64 + kgrp4;
        long rg = ((long)b0 + riX) * NNBR + rowA;
        const float* p; int off;
        if (k < NDIM)             { p = nbr_node  + rg * NDIM; off = k; }
        else if (k < NDIM + EDIM) { p = edge_feat + rg * EDIM; off = k - NDIM; }
        else { p = nbr_time + rg * TDIM; off = k - NDIM - EDIM;
               if (off > TDIM - 4) off = TDIM - 4; }   // pad: garbage x W=0
        return *(const float4*)(p + off);
    };

    // ---- prologue: iteration 0's 7 tiles in flight (the latency buffer)
    float4 rs[NT];
    #pragma unroll
    for (int t = 0; t < NT; t++) rs[t] = loadA(0, t);
    __builtin_amdgcn_sched_barrier(0);

    for (int ri = 0; ri < RPB; ri++) {
        const int riN = (ri + 1 < RPB) ? ri + 1 : RPB - 1;  // clamp (extra reads ok)
        f32x4 acc[2][2];
        #pragma unroll
        for (int m = 0; m < 2; m++)
            #pragma unroll
            for (int n = 0; n < 2; n++) acc[m][n] = (f32x4){0.f, 0.f, 0.f, 0.f};

        #pragma unroll
        for (int t = 0; t < NT; t++) {
            unsigned char* aw = smem + A_OFF + (t & 1) * 4096;
            // stage tile (ri,t): loaded 7 tiles ago -> counted vmcnt wait
            {
                float4 v = rs[t];
                uint2 w;
                w.x = (unsigned)bfb(v.x) | ((unsigned)bfb(v.y) << 16);
                w.y = (unsigned)bfb(v.z) | ((unsigned)bfb(v.w) << 16);
                *(uint2*)(aw + awb) = w;
            }
            rs[t] = loadA(riN, t);            // refill: iter ri+1, same tile
            __builtin_amdgcn_sched_barrier(0);
            BARRIER();                         // exchange visible; vmem stays in flight
            // compute tile t: phases 2t, 2t+1 (W from registers)
            #pragma unroll
            for (int kk = 0; kk < 2; kk++) {
                bf16x8 af[2];
                #pragma unroll
                for (int m = 0; m < 2; m++) {
                    int row = m * 16 + (lane & 15);
                    af[m] = __builtin_bit_cast(bf16x8, *(const short8*)(
                        aw + row * 128 + ((kk * 64 + (lane >> 4) * 16) ^ ((row & 7) << 4))));
                }
                const int p = t * 2 + kk;
                acc[0][0] = __builtin_amdgcn_mfma_f32_16x16x32_bf16(af[0], Wr[p*2+0], acc[0][0], 0, 0, 0);
                acc[0][1] = __builtin_amdgcn_mfma_f32_16x16x32_bf16(af[0], Wr[p*2+1], acc[0][1], 0, 0, 0);
                acc[1][0] = __builtin_amdgcn_mfma_f32_16x16x32_bf16(af[1], Wr[p*2+0], acc[1][0], 0, 0, 0);
                acc[1][1] = __builtin_amdgcn_mfma_f32_16x16x32_bf16(af[1], Wr[p*2+1], acc[1][1], 0, 0, 0);
            }
        }

        // ---- dump Z row-block (+bkv); C/D: col=lane&15, row=(lane>>4)*4+j
        const int gi = ri & 3;
        #pragma unroll
        for (int n = 0; n < 2; n++) {
            int col = wid * 32 + n * 16 + (lane & 15);
            float bk = n ? bk1 : bk0;
            #pragma unroll
            for (int m = 0; m < 2; m++)
                #pragma unroll
                for (int j = 0; j < 4; j++) {
                    int rowZ = gi * 32 + m * 16 + (lane >> 4) * 4 + j;
                    *(unsigned short*)(smem + ZB(rowZ, col)) = bfb(acc[m][n][j] + bk);
                }
        }

        if (gi == 3) {
            const int g = ri >> 2;             // tail group 0/1 (uniform)
            BARRIER();                          // dumps visible; A loads keep flying

            // ---- scores + softmax (R4-proven): wid -> (bl=wid>>1, h=wid&1)
            {
                int bl = wid >> 1, h = wid & 1;
                int n2 = lane >> 1, half = lane & 1;
                int np = h * 16 + (n2 >> 1);
                int rowZ = bl * NNBR + np;
                int cb = (n2 & 1) * 64 + half * 32;
                const float* q = qresL + (g * 4 + bl) * ODIM + h * 64 + half * 32;
                float s = 0.f;
                #pragma unroll
                for (int j = 0; j < 4; j++) {
                    short8 z8 = *(const short8*)(smem + ZB(rowZ, cb + j * 8));
                    #pragma unroll
                    for (int e = 0; e < 8; e++)
                        s += q[j * 8 + e] * bf2f((unsigned short)z8[e]);
                }
                s += __shfl_xor(s, 1);
                s *= 0.125f;
                if (maskL[(g * 4 + bl) * NNBR + n2] == 0) s = -1e10f;
                float mx = s;
                #pragma unroll
                for (int off = 1; off < 64; off <<= 1) mx = fmaxf(mx, __shfl_xor(mx, off));
                float e = __expf(s - mx);
                float sum = e;
                #pragma unroll
                for (int off = 1; off < 64; off <<= 1) sum += __shfl_xor(sum, off);
                float pv = e * 2.f / sum;
                if (half == 0) Pband[(bl * 2 + h) * NNBR + n2] = pv;
            }
            BARRIER();

            // ---- O = P @ V
            {
                int b = tid >> 7, c = tid & 127, h = c >> 6, d = c & 63;
                const float* P = Pband + (b * 2 + h) * NNBR;
                float s = 0.f;
                #pragma unroll
                for (int n2 = 0; n2 < NNBR; n2++) {
                    int np = h * 16 + (n2 >> 1);
                    int col = ODIM + (n2 & 1) * 64 + d;
                    s += P[n2] * bf2f(*(const unsigned short*)(smem + ZB(b * NNBR + np, col)));
                }
                Obuf[b * ODIM + c] = s;
            }
            BARRIER();

            // ---- out proj + LayerNorm
            {
                int b = tid >> 7, c = tid & 127;
                float s = bo[c];
                const float* ob = Obuf + b * ODIM;
                #pragma unroll 8
                for (int k = 0; k < ODIM; k++)
                    s += ob[k] * bf2f(woT[k * 128 + c]);
                float s1 = s, s2 = s * s;
                #pragma unroll
                for (int off = 1; off < 64; off <<= 1) {
                    s1 += __shfl_xor(s1, off);
                    s2 += __shfl_xor(s2, off);
                }
                if (lane == 0) { red[wid * 2] = s1; red[wid * 2 + 1] = s2; }
                BARRIER();
                float t1 = red[b * 4 + 0] + red[b * 4 + 2];
                float t2 = red[b * 4 + 1] + red[b * 4 + 3];
                float mu  = t1 * (1.f / 128.f);
                float var = t2 * (1.f / 128.f) - mu * mu;
                float inv = rsqrtf(var + LN_EPS);
                out[(long)(b0 + g * 4 + b) * ODIM + c] = (s - mu) * inv * gamma[c] + beta[c];
            }
            BARRIER();   // tail done before next group's dumps reuse Z
        }
    }
}

extern "C" void kernel_launch(void* const* d_in, const int* in_sizes, int n_in,
                              void* d_out, int out_size, void* d_ws, size_t ws_size,
                              hipStream_t stream) {
    const float* node_feat = (const float*)d_in[0];
    const float* time_feat = (const float*)d_in[1];
    const float* edge_feat = (const float*)d_in[2];
    const float* nbr_node  = (const float*)d_in[3];
    const float* nbr_time  = (const float*)d_in[4];
    const int*   nbr_mask  = (const int*)d_in[5];
    const float* Wq   = (const float*)d_in[6];
    const float* bq   = (const float*)d_in[7];
    const float* Wkv  = (const float*)d_in[8];
    const float* bkv  = (const float*)d_in[9];
    const float* Wo   = (const float*)d_in[10];
    const float* bo   = (const float*)d_in[11];
    const float* gma  = (const float*)d_in[12];
    const float* bta  = (const float*)d_in[13];
    float* out = (float*)d_out;

    const int B = in_sizes[0] / NDIM;  // 8192

    // workspace layout
    char* ws = (char*)d_ws;
    float* Qbuf = (float*)ws;                                   // B*128*4 = 4 MB
    unsigned short* wfrag = (unsigned short*)(ws + (size_t)B * ODIM * 4);
    unsigned short* wqT   = wfrag + WFRAG_N;
    unsigned short* woT   = wqT + WQT_N;

    hipFuncSetAttribute((const void*)ta_fused,
                        hipFuncAttributeMaxDynamicSharedMemorySize, SMEM_BYTES);

    const int prep_total = WFRAG_N + WQT_N + WOT_N;
    prep_pack<<<dim3((prep_total + 255) / 256), dim3(256), 0, stream>>>(
        Wkv, Wq, Wo, wfrag, wqT, woT);
    q_proj<<<dim3(B / 8), dim3(256), 0, stream>>>(node_feat, time_feat, wqT, bq, Qbuf);
    ta_fused<<<dim3(B / RPB), dim3(512), SMEM_BYTES, stream>>>(
        edge_feat, nbr_node, nbr_time, nbr_mask, Qbuf,
        wfrag, bkv, woT, bo, gma, bta, out);
}